// Round 11
// baseline (177.092 us; speedup 1.0000x reference)
//
#include <hip/hip_runtime.h>
#include <hip/hip_bf16.h>
#include <hip/hip_cooperative_groups.h>
#include <math.h>

namespace cg = cooperative_groups;

typedef __attribute__((ext_vector_type(8))) short short8;
typedef __attribute__((ext_vector_type(4))) float f32x4;

#define NB 8192
#define ND 256
#define NT3 32            // 256-row tiles per side (528 triangle tiles)
#define LN2f 0.6931471805599453f

__device__ __forceinline__ float bf2f(ushort u) {
  unsigned int x = ((unsigned int)u) << 16;
  return __builtin_bit_cast(float, x);
}
__device__ __forceinline__ ushort f2bf(float x) {
  return __builtin_bit_cast(ushort, __float2bfloat16(x));
}

// stage a 256-row x K64 slab (32KB) into LDS [ku8][row256], linear dest
__device__ __forceinline__ void stage256(ushort* lds, const ushort* __restrict__ hsK,
                                         int t128a, int ch, int tid) {
#pragma unroll
  for (int i = 0; i < 4; ++i) {
    int U = i * 512 + tid;           // LDS 16B-unit index, 0..2047
    int ku = U >> 8;                 // 0..7
    int row = U & 255;               // 0..255
    int t = t128a + (row >> 7);
    const ushort* gp = hsK + ((size_t)t * 4096 + (ch * 8 + ku) * 128 + (row & 127)) * 8;
    __builtin_amdgcn_global_load_lds(
        (const __attribute__((address_space(1))) unsigned int*)gp,
        (__attribute__((address_space(3))) unsigned int*)(lds + (size_t)U * 8),
        16, 0, 0);
  }
}

__global__ __launch_bounds__(512)
__attribute__((amdgpu_waves_per_eu(2)))
void fused_kernel(const float* __restrict__ h, const int* __restrict__ labels,
                  ushort* __restrict__ hs, ushort* __restrict__ hsK,
                  float* __restrict__ dbuf, float* __restrict__ Cs,
                  float* __restrict__ cntf, float* __restrict__ rowpart,
                  float* __restrict__ colpart, float2* __restrict__ bsum,
                  float* __restrict__ out) {
  __shared__ ushort AB[2][2][16384];   // 128 KB: [A/B][dbuf][32KB]
  __shared__ int list[256];
  __shared__ int wscan[8];
  __shared__ float lred[16];

  cg::grid_group grid = cg::this_grid();
  const int b = blockIdx.x, tid = threadIdx.x;
  const int lane = tid & 63, wave = tid >> 6;
  const int g = lane >> 4, cl = lane & 15;
  const float SCALE = 1.0f / sqrtf(0.07f * LN2f);

  // ---------- phase 1: norm + K-major transpose + dbuf (32 rows/block) ------
#pragma unroll
  for (int i = 0; i < 4; ++i) {
    int r = b * 32 + wave * 4 + i;
    float4 v = reinterpret_cast<const float4*>(h + (size_t)r * ND)[lane];
    float ss = v.x * v.x + v.y * v.y + v.z * v.z + v.w * v.w;
#pragma unroll
    for (int d = 1; d <= 32; d <<= 1) ss += __shfl_xor(ss, d);
    float scale = SCALE / fmaxf(sqrtf(ss), 1e-12f);
    ushort4 o;
    o.x = f2bf(v.x * scale); o.y = f2bf(v.y * scale);
    o.z = f2bf(v.z * scale); o.w = f2bf(v.w * scale);
    reinterpret_cast<ushort4*>(hs + (size_t)r * ND)[lane] = o;
    *reinterpret_cast<ushort4*>(
        hsK + ((size_t)((r >> 7) * 32 + (lane >> 1)) * 128 + (r & 127)) * 8 +
        (lane & 1) * 4) = o;
    float qx = bf2f(o.x), qy = bf2f(o.y), qz = bf2f(o.z), qw = bf2f(o.w);
    float dd = qx * qx + qy * qy + qz * qz + qw * qw;
#pragma unroll
    for (int d = 1; d <= 32; d <<= 1) dd += __shfl_xor(dd, d);
    if (lane == 0) dbuf[r] = dd;
  }
  grid.sync();

  // ---------- phase 2a: classsum (blocks 0..99), deterministic scan ---------
  if (b < 100) {
    int c = b;
    int base0 = tid * 16;
    int mycnt = 0;
#pragma unroll
    for (int i2 = 0; i2 < 16; ++i2) mycnt += (labels[base0 + i2] == c) ? 1 : 0;
    int inc = mycnt;
#pragma unroll
    for (int d = 1; d < 64; d <<= 1) {
      int v2 = __shfl_up(inc, d);
      if (lane >= d) inc += v2;
    }
    if (lane == 63) wscan[wave] = inc;
    __syncthreads();
    int wbase = 0, ntot = 0;
#pragma unroll
    for (int w = 0; w < 8; ++w) {
      wbase += (w < wave) ? wscan[w] : 0;
      ntot += wscan[w];
    }
    int off = wbase + inc - mycnt;
    for (int i2 = 0; i2 < 16; ++i2) {
      int idx = base0 + i2;
      if (labels[idx] == c) list[off++] = idx;
    }
    __syncthreads();
    int rh = tid >> 8, col = tid & 255;
    float a0 = 0.f;
    for (int k = rh; k < ntot; k += 2)
      a0 += bf2f(hs[(size_t)list[k] * ND + col]);
    float* carr = reinterpret_cast<float*>(&AB[0][0][0]);
    carr[rh * 256 + col] = a0;
    __syncthreads();
    if (rh == 0) Cs[c * ND + col] = carr[col] + carr[256 + col];
    if (tid == 0) cntf[c] = (float)ntot;
  }

  // ---------- phase 2b: main 256x256 triangle tiles (persistent) ------------
#pragma unroll 1
  for (int sel = 0; sel < 3; ++sel) {
    int tindex;
    if (sel == 0) tindex = b;
    else if (sel == 1) tindex = b + 256;
    else tindex = (b >= 100 && b < 116) ? 512 + (b - 100) : -1;
    if (tindex < 0) continue;

    int nid = (tindex & 7) * 66 + (tindex >> 3);   // bijective (528 = 8*66)
    int rb = 0, t2 = nid;
    while (t2 >= NT3 - rb) { t2 -= NT3 - rb; ++rb; }
    int cb = rb + t2;
    bool diag = (rb == cb);
    int wr = (wave >> 2) * 128, wc = (wave & 3) * 64;

    __syncthreads();   // prior LDS uses (carr / previous tile red) complete
    stage256(&AB[0][0][0], hsK, rb * 2, 0, tid);
    if (!diag) stage256(&AB[1][0][0], hsK, cb * 2, 0, tid);
    __syncthreads();

    f32x4 acc[8][4];
#pragma unroll
    for (int rf = 0; rf < 8; ++rf)
#pragma unroll
      for (int cf = 0; cf < 4; ++cf) acc[rf][cf] = (f32x4){0.f, 0.f, 0.f, 0.f};

#pragma unroll
    for (int ch = 0; ch < 4; ++ch) {
      if (ch < 3) {
        stage256(&AB[0][(ch + 1) & 1][0], hsK, rb * 2, ch + 1, tid);
        if (!diag) stage256(&AB[1][(ch + 1) & 1][0], hsK, cb * 2, ch + 1, tid);
      }
      const ushort* At = &AB[0][ch & 1][0];
      const ushort* Bt = diag ? At : &AB[1][ch & 1][0];
#pragma unroll
      for (int ks = 0; ks < 2; ++ks) {
        short8 bf[4];
#pragma unroll
        for (int cf = 0; cf < 4; ++cf)
          bf[cf] = *reinterpret_cast<const short8*>(
              Bt + ((ks * 4 + g) * 256 + wc + cf * 16 + cl) * 8);
#pragma unroll
        for (int rf = 0; rf < 8; ++rf) {
          short8 a = *reinterpret_cast<const short8*>(
              At + ((ks * 4 + g) * 256 + wr + rf * 16 + cl) * 8);
#pragma unroll
          for (int cf = 0; cf < 4; ++cf)
            acc[rf][cf] = __builtin_amdgcn_mfma_f32_16x16x32_bf16(
                a, bf[cf], acc[rf][cf], 0, 0, 0);
        }
      }
      __syncthreads();   // drains prefetch vmcnt + protects buffers
    }

    // epilogue: exp2 sums -> row partials (cf,cl) and col partials (rf,q,g)
    float sr[32], cc[4];
#pragma unroll
    for (int i = 0; i < 32; ++i) sr[i] = 0.f;
#pragma unroll
    for (int i = 0; i < 4; ++i) cc[i] = 0.f;
#pragma unroll
    for (int rf = 0; rf < 8; ++rf)
#pragma unroll
      for (int cf = 0; cf < 4; ++cf)
#pragma unroll
        for (int q = 0; q < 4; ++q) {
          float e = __builtin_amdgcn_exp2f(acc[rf][cf][q]);
          sr[rf * 4 + q] += e;
          cc[cf] += e;
        }
#pragma unroll
    for (int i = 0; i < 32; ++i) {
#pragma unroll
      for (int d = 1; d <= 8; d <<= 1) sr[i] += __shfl_xor(sr[i], d);
    }
#pragma unroll
    for (int i = 0; i < 4; ++i) {
      cc[i] += __shfl_xor(cc[i], 16);
      cc[i] += __shfl_xor(cc[i], 32);
    }
    float* red = reinterpret_cast<float*>(&AB[0][0][0]);
    float* sred = red;          // [8 waves][128 rows]
    float* cred = red + 1024;   // [8 waves][64 cols]
    if (cl == 0) {
#pragma unroll
      for (int rf = 0; rf < 8; ++rf)
#pragma unroll
        for (int q = 0; q < 4; ++q)
          sred[wave * 128 + rf * 16 + g * 4 + q] = sr[rf * 4 + q];
    }
    if (g == 0) {
#pragma unroll
      for (int cf = 0; cf < 4; ++cf) cred[wave * 64 + cf * 16 + cl] = cc[cf];
    }
    __syncthreads();
    if (tid < 256) {
      int r = tid, half = r >> 7, rl2 = r & 127;
      float rv = sred[(half * 4 + 0) * 128 + rl2] + sred[(half * 4 + 1) * 128 + rl2] +
                 sred[(half * 4 + 2) * 128 + rl2] + sred[(half * 4 + 3) * 128 + rl2];
      rowpart[(size_t)cb * NB + rb * 256 + r] = rv;
    } else if (!diag) {
      int c2 = tid - 256, wgrp = c2 >> 6, cl2 = c2 & 63;
      float cv = cred[wgrp * 64 + cl2] + cred[(4 + wgrp) * 64 + cl2];
      colpart[(size_t)rb * NB + cb * 256 + c2] = cv;
    }
  }
  grid.sync();

  // ---------- phase 3: per-row loss (32 rows/block) -------------------------
  float accL = 0.f, accV = 0.f;
#pragma unroll
  for (int i = 0; i < 4; ++i) {
    int row = b * 32 + wave * 4 + i;
    int lbl = labels[row];
    ushort4 qb = reinterpret_cast<const ushort4*>(hs + (size_t)row * ND)[lane];
    float4 cv = reinterpret_cast<const float4*>(Cs + (size_t)lbl * ND)[lane];
    float dot = bf2f(qb.x) * cv.x + bf2f(qb.y) * cv.y +
                bf2f(qb.z) * cv.z + bf2f(qb.w) * cv.w;
#pragma unroll
    for (int d = 1; d <= 32; d <<= 1) dot += __shfl_xor(dot, d);
    int rb0 = row >> 8;
    float part = 0.f;
    if (lane < NT3) {
      const float* basep = (lane >= rb0) ? rowpart : colpart;
      part = basep[(size_t)lane * NB + row];
    }
#pragma unroll
    for (int d = 1; d <= 16; d <<= 1) part += __shfl_xor(part, d);
    if (lane == 0) {
      float dself = dbuf[row];
      float s = part - (1.0f - 1e-8f) * __builtin_amdgcn_exp2f(dself);
      float denom2 = log2f(s);
      float Sp2 = dot - dself;
      float n = cntf[lbl] - 1.0f;
      if (n > 0.5f) { accL += -LN2f * (Sp2 - n * denom2) / n; accV += 1.f; }
    }
  }
  if (lane == 0) { lred[wave * 2] = accL; lred[wave * 2 + 1] = accV; }
  __syncthreads();
  if (tid == 0) {
    float L = 0.f, V = 0.f;
#pragma unroll
    for (int w = 0; w < 8; ++w) { L += lred[w * 2]; V += lred[w * 2 + 1]; }
    bsum[b] = make_float2(L, V);
  }
  grid.sync();

  // ---------- phase 4: final scalar ----------------------------------------
  if (b == 0) {
    float L = 0.f, V = 0.f;
    if (tid < 256) { float2 p = bsum[tid]; L = p.x; V = p.y; }
#pragma unroll
    for (int d = 1; d <= 32; d <<= 1) { L += __shfl_xor(L, d); V += __shfl_xor(V, d); }
    __syncthreads();   // lred re-use
    if (lane == 0) { lred[wave * 2] = L; lred[wave * 2 + 1] = V; }
    __syncthreads();
    if (tid == 0) {
      float Ls = 0.f, Vs = 0.f;
#pragma unroll
      for (int w = 0; w < 8; ++w) { Ls += lred[w * 2]; Vs += lred[w * 2 + 1]; }
      out[0] = Ls / fmaxf(Vs, 1.f);
    }
  }
}

extern "C" void kernel_launch(void* const* d_in, const int* in_sizes, int n_in,
                              void* d_out, int out_size, void* d_ws, size_t ws_size,
                              hipStream_t stream) {
  const float* hidden = (const float*)d_in[0];
  const int* labels = (const int*)d_in[1];
  float* out = (float*)d_out;
  char* w = (char*)d_ws;
  ushort* hsK    = (ushort*)(w);                 // 4 MB
  ushort* hs     = (ushort*)(w + 4194304);       // 4 MB
  float* dbuf    = (float*)(w + 8388608);        // 32 KB
  float* Cs      = (float*)(w + 8421376);        // 100 KB
  float* cntf    = (float*)(w + 8523776);        // 512 B
  float* rowpart = (float*)(w + 8524288);        // 1 MB
  float* colpart = (float*)(w + 9572864);        // 1 MB
  float2* bsum   = (float2*)(w + 10621440);      // 2 KB

  void* args[] = {(void*)&hidden, (void*)&labels, (void*)&hs, (void*)&hsK,
                  (void*)&dbuf, (void*)&Cs, (void*)&cntf, (void*)&rowpart,
                  (void*)&colpart, (void*)&bsum, (void*)&out};
  hipLaunchCooperativeKernel(reinterpret_cast<void*>(fused_kernel),
                             dim3(256), dim3(512), args, 0, stream);
}

// Round 12
// 156.165 us; speedup vs baseline: 1.1340x; 1.1340x over previous
//
#include <hip/hip_runtime.h>
#include <hip/hip_bf16.h>
#include <hip/hip_cooperative_groups.h>
#include <math.h>

namespace cg = cooperative_groups;

typedef __attribute__((ext_vector_type(8))) short short8;
typedef __attribute__((ext_vector_type(4))) float f32x4;

#define NB 8192
#define ND 256
#define NBT 1056          // tiles: sum_{rb=0}^{63} (32 - rb/2)
#define LN2f 0.6931471805599453f

__device__ __forceinline__ float bf2f(ushort u) {
  unsigned int x = ((unsigned int)u) << 16;
  return __builtin_bit_cast(float, x);
}
__device__ __forceinline__ ushort f2bf(float x) {
  return __builtin_bit_cast(ushort, __float2bfloat16(x));
}

// A chunk: hsK[rb][ku=ch*8..+7][row 0..127] — contiguous 16KB, linear copy
__device__ __forceinline__ void stageA(ushort* lds, const ushort* __restrict__ hsK,
                                       int rb, int ch, int tid) {
  const ushort* gp = hsK + ((size_t)rb * 4096 + ch * 1024) * 8;
#pragma unroll
  for (int i = 0; i < 2; ++i) {
    int U = i * 512 + tid;
    __builtin_amdgcn_global_load_lds(
        (const __attribute__((address_space(1))) unsigned int*)(gp + (size_t)U * 8),
        (__attribute__((address_space(3))) unsigned int*)(lds + (size_t)U * 8),
        16, 0, 0);
  }
}
// B chunk: rows 0..255 from row-tiles 2cb,2cb+1; LDS [ku8][row256]
__device__ __forceinline__ void stageB(ushort* lds, const ushort* __restrict__ hsK,
                                       int cb, int ch, int tid) {
#pragma unroll
  for (int i = 0; i < 4; ++i) {
    int U = i * 512 + tid;            // U = ku*256 + row
    int ku = U >> 8, row = U & 255;
    int half = row >> 7, rl = row & 127;
    const ushort* gp =
        hsK + ((size_t)(cb * 2 + half) * 4096 + (ch * 8 + ku) * 128 + rl) * 8;
    __builtin_amdgcn_global_load_lds(
        (const __attribute__((address_space(1))) unsigned int*)gp,
        (__attribute__((address_space(3))) unsigned int*)(lds + (size_t)U * 8),
        16, 0, 0);
  }
}

__global__ __launch_bounds__(512)
void fused_kernel(const float* __restrict__ h, const int* __restrict__ labels,
                  ushort* __restrict__ hs, ushort* __restrict__ hsK,
                  float* __restrict__ dbuf, float* __restrict__ Cs,
                  float* __restrict__ cntf, float* __restrict__ rowpart,
                  float* __restrict__ colpart, float2* __restrict__ bsum,
                  float* __restrict__ out) {
  __shared__ ushort Abuf[2][8192];    // 2 x 16KB
  __shared__ ushort Bbuf[2][16384];   // 2 x 32KB
  __shared__ int list[256];
  __shared__ int wscan[8];
  __shared__ float lred[16];

  cg::grid_group grid = cg::this_grid();
  const int b = blockIdx.x, tid = threadIdx.x;
  const int lane = tid & 63, wave = tid >> 6;
  const int g = lane >> 4, cl = lane & 15;
  const float SCALE = 1.0f / sqrtf(0.07f * LN2f);

  // ---------- phase 1: norm + K-major transpose + dbuf (32 rows/block) ------
#pragma unroll
  for (int i = 0; i < 4; ++i) {
    int r = b * 32 + wave * 4 + i;
    float4 v = reinterpret_cast<const float4*>(h + (size_t)r * ND)[lane];
    float ss = v.x * v.x + v.y * v.y + v.z * v.z + v.w * v.w;
#pragma unroll
    for (int d = 1; d <= 32; d <<= 1) ss += __shfl_xor(ss, d);
    float scale = SCALE / fmaxf(sqrtf(ss), 1e-12f);
    ushort4 o;
    o.x = f2bf(v.x * scale); o.y = f2bf(v.y * scale);
    o.z = f2bf(v.z * scale); o.w = f2bf(v.w * scale);
    reinterpret_cast<ushort4*>(hs + (size_t)r * ND)[lane] = o;
    *reinterpret_cast<ushort4*>(
        hsK + ((size_t)((r >> 7) * 32 + (lane >> 1)) * 128 + (r & 127)) * 8 +
        (lane & 1) * 4) = o;
    float qx = bf2f(o.x), qy = bf2f(o.y), qz = bf2f(o.z), qw = bf2f(o.w);
    float dd = qx * qx + qy * qy + qz * qz + qw * qw;
#pragma unroll
    for (int d = 1; d <= 32; d <<= 1) dd += __shfl_xor(dd, d);
    if (lane == 0) dbuf[r] = dd;
  }
  grid.sync();

  // ---------- phase 2a: classsum (blocks 0..99), deterministic scan ---------
  if (b < 100) {
    int c = b;
    int base0 = tid * 16;
    int mycnt = 0;
#pragma unroll
    for (int i2 = 0; i2 < 16; ++i2) mycnt += (labels[base0 + i2] == c) ? 1 : 0;
    int inc = mycnt;
#pragma unroll
    for (int d = 1; d < 64; d <<= 1) {
      int v2 = __shfl_up(inc, d);
      if (lane >= d) inc += v2;
    }
    if (lane == 63) wscan[wave] = inc;
    __syncthreads();
    int wbase = 0, ntot = 0;
#pragma unroll
    for (int w = 0; w < 8; ++w) {
      wbase += (w < wave) ? wscan[w] : 0;
      ntot += wscan[w];
    }
    int off = wbase + inc - mycnt;
    for (int i2 = 0; i2 < 16; ++i2) {
      int idx = base0 + i2;
      if (labels[idx] == c) list[off++] = idx;
    }
    __syncthreads();
    int rh = tid >> 8, col = tid & 255;
    float a0 = 0.f;
    for (int k = rh; k < ntot; k += 2)
      a0 += bf2f(hs[(size_t)list[k] * ND + col]);
    float* carr = reinterpret_cast<float*>(&Abuf[0][0]);
    carr[rh * 256 + col] = a0;
    __syncthreads();
    if (rh == 0) Cs[c * ND + col] = carr[col] + carr[256 + col];
    if (tid == 0) cntf[c] = (float)ntot;
  }

  // ---------- phase 2b: 128x256 triangle tiles (persistent) -----------------
#pragma unroll 1
  for (int sel = 0; sel < 5; ++sel) {
    int tindex;
    if (sel < 4) tindex = b + sel * 256;
    else tindex = (b >= 224) ? 1024 + (b - 224) : -1;
    if (tindex < 0 || tindex >= NBT) continue;

    int nid = (tindex & 7) * 132 + (tindex >> 3);   // bijective (1056 = 8*132)
    int rb = 0, t2 = nid;
    while (t2 >= 32 - (rb >> 1)) { t2 -= 32 - (rb >> 1); ++rb; }
    int cb = (rb >> 1) + t2;
    bool diagish = (cb == (rb >> 1));
    int wrow = (wave >> 2) * 64, wcol = (wave & 3) * 64;

    __syncthreads();   // prior LDS readers (carr / prev tile red) done
    stageA(&Abuf[0][0], hsK, rb, 0, tid);
    stageB(&Bbuf[0][0], hsK, cb, 0, tid);
    __syncthreads();

    f32x4 acc[4][4];
#pragma unroll
    for (int rf = 0; rf < 4; ++rf)
#pragma unroll
      for (int cf = 0; cf < 4; ++cf) acc[rf][cf] = (f32x4){0.f, 0.f, 0.f, 0.f};

#pragma unroll
    for (int ch = 0; ch < 4; ++ch) {
      if (ch < 3) {
        stageA(&Abuf[(ch + 1) & 1][0], hsK, rb, ch + 1, tid);
        stageB(&Bbuf[(ch + 1) & 1][0], hsK, cb, ch + 1, tid);
      }
      const ushort* At = &Abuf[ch & 1][0];
      const ushort* Bt = &Bbuf[ch & 1][0];
#pragma unroll
      for (int ks = 0; ks < 2; ++ks) {
        short8 bf[4];
#pragma unroll
        for (int cf = 0; cf < 4; ++cf)
          bf[cf] = *reinterpret_cast<const short8*>(
              Bt + ((ks * 4 + g) * 256 + wcol + cf * 16 + cl) * 8);
#pragma unroll
        for (int rf = 0; rf < 4; ++rf) {
          short8 a = *reinterpret_cast<const short8*>(
              At + ((ks * 4 + g) * 128 + wrow + rf * 16 + cl) * 8);
#pragma unroll
          for (int cf = 0; cf < 4; ++cf)
            acc[rf][cf] = __builtin_amdgcn_mfma_f32_16x16x32_bf16(
                a, bf[cf], acc[rf][cf], 0, 0, 0);
        }
      }
      __syncthreads();   // drains prefetch vmcnt + protects buffers
    }

    // epilogue: exp2 sums -> row partials (over cf,cl) / col partials (rf,q,g)
    float sr[16], cc[4];
#pragma unroll
    for (int i = 0; i < 16; ++i) sr[i] = 0.f;
#pragma unroll
    for (int i = 0; i < 4; ++i) cc[i] = 0.f;
#pragma unroll
    for (int rf = 0; rf < 4; ++rf)
#pragma unroll
      for (int cf = 0; cf < 4; ++cf)
#pragma unroll
        for (int q = 0; q < 4; ++q) {
          float e = __builtin_amdgcn_exp2f(acc[rf][cf][q]);
          sr[rf * 4 + q] += e;
          cc[cf] += e;
        }
#pragma unroll
    for (int i = 0; i < 16; ++i) {
#pragma unroll
      for (int d = 1; d <= 8; d <<= 1) sr[i] += __shfl_xor(sr[i], d);
    }
#pragma unroll
    for (int i = 0; i < 4; ++i) {
      cc[i] += __shfl_xor(cc[i], 16);
      cc[i] += __shfl_xor(cc[i], 32);
    }
    float* sred = reinterpret_cast<float*>(&Abuf[0][0]);  // [8 waves][64 rows]
    float* cred = sred + 512;                             // [8 waves][64 cols]
    if (cl == 0) {
#pragma unroll
      for (int rf = 0; rf < 4; ++rf)
#pragma unroll
        for (int q = 0; q < 4; ++q)
          sred[wave * 64 + rf * 16 + g * 4 + q] = sr[rf * 4 + q];
    }
    if (g == 0) {
#pragma unroll
      for (int cf = 0; cf < 4; ++cf) cred[wave * 64 + cf * 16 + cl] = cc[cf];
    }
    __syncthreads();
    if (tid < 128) {
      int r = tid, half = r >> 6, rl2 = r & 63;
      float rv = sred[(half * 4 + 0) * 64 + rl2] + sred[(half * 4 + 1) * 64 + rl2] +
                 sred[(half * 4 + 2) * 64 + rl2] + sred[(half * 4 + 3) * 64 + rl2];
      rowpart[(size_t)cb * NB + rb * 128 + r] = rv;
    } else if (tid < 384 && !diagish) {
      int c2 = tid - 128;               // 0..255
      int cg2 = c2 >> 6, cl2 = c2 & 63;
      float cv = cred[cg2 * 64 + cl2] + cred[(cg2 + 4) * 64 + cl2];
      colpart[(size_t)rb * NB + cb * 256 + c2] = cv;
    }
  }
  grid.sync();

  // ---------- phase 3: per-row loss (32 rows/block) -------------------------
  float accL = 0.f, accV = 0.f;
#pragma unroll
  for (int i = 0; i < 4; ++i) {
    int row = b * 32 + wave * 4 + i;
    int lbl = labels[row];
    ushort4 qb = reinterpret_cast<const ushort4*>(hs + (size_t)row * ND)[lane];
    float4 cv = reinterpret_cast<const float4*>(Cs + (size_t)lbl * ND)[lane];
    float dot = bf2f(qb.x) * cv.x + bf2f(qb.y) * cv.y +
                bf2f(qb.z) * cv.z + bf2f(qb.w) * cv.w;
#pragma unroll
    for (int d = 1; d <= 32; d <<= 1) dot += __shfl_xor(dot, d);
    int cr = row >> 8;                  // 256-col tile of this row
    float part = 0.f;
    if (lane < 32) {
      if (lane >= cr) part = rowpart[(size_t)lane * NB + row];
    } else {
      int k1 = (lane - 32) * 2;
      if (k1 < 2 * cr) part = colpart[(size_t)k1 * NB + row];
      if (k1 + 1 < 2 * cr) part += colpart[(size_t)(k1 + 1) * NB + row];
    }
#pragma unroll
    for (int d = 1; d <= 32; d <<= 1) part += __shfl_xor(part, d);
    if (lane == 0) {
      float dself = dbuf[row];
      float s = part - (1.0f - 1e-8f) * __builtin_amdgcn_exp2f(dself);
      float denom2 = log2f(s);
      float Sp2 = dot - dself;
      float n = cntf[lbl] - 1.0f;
      if (n > 0.5f) { accL += -LN2f * (Sp2 - n * denom2) / n; accV += 1.f; }
    }
  }
  if (lane == 0) { lred[wave * 2] = accL; lred[wave * 2 + 1] = accV; }
  __syncthreads();
  if (tid == 0) {
    float L = 0.f, V = 0.f;
#pragma unroll
    for (int w = 0; w < 8; ++w) { L += lred[w * 2]; V += lred[w * 2 + 1]; }
    bsum[b] = make_float2(L, V);
  }
  grid.sync();

  // ---------- phase 4: final scalar ----------------------------------------
  if (b == 0) {
    float L = 0.f, V = 0.f;
    if (tid < 256) { float2 p = bsum[tid]; L = p.x; V = p.y; }
#pragma unroll
    for (int d = 1; d <= 32; d <<= 1) { L += __shfl_xor(L, d); V += __shfl_xor(V, d); }
    __syncthreads();
    if (lane == 0) { lred[wave * 2] = L; lred[wave * 2 + 1] = V; }
    __syncthreads();
    if (tid == 0) {
      float Ls = 0.f, Vs = 0.f;
#pragma unroll
      for (int w = 0; w < 8; ++w) { Ls += lred[w * 2]; Vs += lred[w * 2 + 1]; }
      out[0] = Ls / fmaxf(Vs, 1.f);
    }
  }
}

extern "C" void kernel_launch(void* const* d_in, const int* in_sizes, int n_in,
                              void* d_out, int out_size, void* d_ws, size_t ws_size,
                              hipStream_t stream) {
  const float* hidden = (const float*)d_in[0];
  const int* labels = (const int*)d_in[1];
  float* out = (float*)d_out;
  char* w = (char*)d_ws;
  ushort* hsK    = (ushort*)(w);                 // 4 MB
  ushort* hs     = (ushort*)(w + 4194304);       // 4 MB
  float* dbuf    = (float*)(w + 8388608);        // 32 KB
  float* Cs      = (float*)(w + 8421376);        // 100 KB
  float* cntf    = (float*)(w + 8523776);        // 512 B
  float* rowpart = (float*)(w + 8524288);        // 1 MB   (32 col-tiles x 8192)
  float* colpart = (float*)(w + 9572864);        // 2 MB   (64 row-tiles x 8192)
  float2* bsum   = (float2*)(w + 11670016);      // 2 KB

  void* args[] = {(void*)&hidden, (void*)&labels, (void*)&hs, (void*)&hsK,
                  (void*)&dbuf, (void*)&Cs, (void*)&cntf, (void*)&rowpart,
                  (void*)&colpart, (void*)&bsum, (void*)&out};
  hipLaunchCooperativeKernel(reinterpret_cast<void*>(fused_kernel),
                             dim3(256), dim3(512), args, 0, stream);
}

// Round 13
// 69.211 us; speedup vs baseline: 2.5587x; 2.2564x over previous
//
#include <hip/hip_runtime.h>
#include <hip/hip_bf16.h>
#include <math.h>

typedef __attribute__((ext_vector_type(8))) short short8;
typedef __attribute__((ext_vector_type(4))) float f32x4;

#define NB 8192
#define ND 256
#define NBT 1056          // triangle tiles: sum_{rb=0}^{63} (32 - rb/2)
#define LN2f 0.6931471805599453f

__device__ __forceinline__ float bf2f(ushort u) {
  unsigned int x = ((unsigned int)u) << 16;
  return __builtin_bit_cast(float, x);
}
__device__ __forceinline__ ushort f2bf(float x) {
  return __builtin_bit_cast(ushort, __float2bfloat16(x));
}

// ---- prep: normalize, fold 1/sqrt(T*ln2), quantize, write hs + hsK + dbuf --
__global__ void prep_kernel(const float* __restrict__ h, ushort* __restrict__ hs,
                            ushort* __restrict__ hsK, float* __restrict__ dbuf) {
  const float SCALE = 1.0f / sqrtf(0.07f * LN2f);
  int lane = threadIdx.x & 63, wave = threadIdx.x >> 6;
  int r = blockIdx.x * 4 + wave;
  float4 v = reinterpret_cast<const float4*>(h + (size_t)r * ND)[lane];
  float ss = v.x * v.x + v.y * v.y + v.z * v.z + v.w * v.w;
#pragma unroll
  for (int d = 1; d <= 32; d <<= 1) ss += __shfl_xor(ss, d);
  float scale = SCALE / fmaxf(sqrtf(ss), 1e-12f);
  ushort4 o;
  o.x = f2bf(v.x * scale); o.y = f2bf(v.y * scale);
  o.z = f2bf(v.z * scale); o.w = f2bf(v.w * scale);
  reinterpret_cast<ushort4*>(hs + (size_t)r * ND)[lane] = o;
  *reinterpret_cast<ushort4*>(
      hsK + ((size_t)((r >> 7) * 32 + (lane >> 1)) * 128 + (r & 127)) * 8 +
      (lane & 1) * 4) = o;
  float qx = bf2f(o.x), qy = bf2f(o.y), qz = bf2f(o.z), qw = bf2f(o.w);
  float dd = qx * qx + qy * qy + qz * qz + qw * qw;
#pragma unroll
  for (int d = 1; d <= 32; d <<= 1) dd += __shfl_xor(dd, d);
  if (lane == 0) dbuf[r] = dd;
}

// A chunk: hsK[rb][ku=ch*8..+7][row 0..127] — contiguous 16KB, linear copy
__device__ __forceinline__ void stageA(ushort* lds, const ushort* __restrict__ hsK,
                                       int rb, int ch, int tid) {
  const ushort* gp = hsK + ((size_t)rb * 4096 + ch * 1024) * 8;
#pragma unroll
  for (int i = 0; i < 2; ++i) {
    int U = i * 512 + tid;
    __builtin_amdgcn_global_load_lds(
        (const __attribute__((address_space(1))) unsigned int*)(gp + (size_t)U * 8),
        (__attribute__((address_space(3))) unsigned int*)(lds + (size_t)U * 8),
        16, 0, 0);
  }
}
// B chunk: rows 0..255 from row-tiles 2cb,2cb+1; LDS [ku8][row256]
__device__ __forceinline__ void stageB(ushort* lds, const ushort* __restrict__ hsK,
                                       int cb, int ch, int tid) {
#pragma unroll
  for (int i = 0; i < 4; ++i) {
    int U = i * 512 + tid;            // U = ku*256 + row
    int ku = U >> 8, row = U & 255;
    int half = row >> 7, rl = row & 127;
    const ushort* gp =
        hsK + ((size_t)(cb * 2 + half) * 4096 + (ch * 8 + ku) * 128 + rl) * 8;
    __builtin_amdgcn_global_load_lds(
        (const __attribute__((address_space(1))) unsigned int*)gp,
        (__attribute__((address_space(3))) unsigned int*)(lds + (size_t)U * 8),
        16, 0, 0);
  }
}

// ---- main: 1056 triangle tile blocks + 100 classsum blocks -----------------
__global__ __launch_bounds__(512)
void main_kernel(const ushort* __restrict__ hsK, const ushort* __restrict__ hs,
                 const int* __restrict__ labels,
                 float* __restrict__ rowpart, float* __restrict__ colpart,
                 float* __restrict__ Cs, float* __restrict__ cntf) {
  __shared__ ushort Abuf[2][8192];    // 2 x 16KB
  __shared__ ushort Bbuf[2][16384];   // 2 x 32KB
  __shared__ int list[256];
  __shared__ int wscan[8];
  int tid = threadIdx.x, lane = tid & 63, wave = tid >> 6;
  int g = lane >> 4, cl = lane & 15;

  if (blockIdx.x >= NBT) {
    // ---------------- classsum for class c (deterministic scan) -------------
    int c = blockIdx.x - NBT;
    int base0 = tid * 16;
    int mycnt = 0;
#pragma unroll
    for (int i2 = 0; i2 < 16; ++i2) mycnt += (labels[base0 + i2] == c) ? 1 : 0;
    int inc = mycnt;
#pragma unroll
    for (int d = 1; d < 64; d <<= 1) {
      int v2 = __shfl_up(inc, d);
      if (lane >= d) inc += v2;
    }
    if (lane == 63) wscan[wave] = inc;
    __syncthreads();
    int wbase = 0, ntot = 0;
#pragma unroll
    for (int w = 0; w < 8; ++w) {
      wbase += (w < wave) ? wscan[w] : 0;
      ntot += wscan[w];
    }
    int off = wbase + inc - mycnt;
    for (int i2 = 0; i2 < 16; ++i2) {
      int idx = base0 + i2;
      if (labels[idx] == c) list[off++] = idx;
    }
    __syncthreads();
    int rh = tid >> 8, col = tid & 255;
    float a0 = 0.f;
    for (int k = rh; k < ntot; k += 2)
      a0 += bf2f(hs[(size_t)list[k] * ND + col]);
    float* carr = reinterpret_cast<float*>(&Abuf[0][0]);
    carr[rh * 256 + col] = a0;
    __syncthreads();
    if (rh == 0) Cs[c * ND + col] = carr[col] + carr[256 + col];
    if (tid == 0) cntf[c] = (float)ntot;
    return;
  }

  // ---------------- 128x256 triangle tile ----------------------------------
  int nid = (blockIdx.x & 7) * 132 + (blockIdx.x >> 3);   // bijective (1056=8*132)
  int rb = 0, t2 = nid;
  while (t2 >= 32 - (rb >> 1)) { t2 -= 32 - (rb >> 1); ++rb; }
  int cb = (rb >> 1) + t2;
  bool diagish = (cb == (rb >> 1));
  int wrow = (wave >> 2) * 64, wcol = (wave & 3) * 64;

  stageA(&Abuf[0][0], hsK, rb, 0, tid);
  stageB(&Bbuf[0][0], hsK, cb, 0, tid);
  __syncthreads();

  f32x4 acc[4][4];
#pragma unroll
  for (int rf = 0; rf < 4; ++rf)
#pragma unroll
    for (int cf = 0; cf < 4; ++cf) acc[rf][cf] = (f32x4){0.f, 0.f, 0.f, 0.f};

#pragma unroll
  for (int ch = 0; ch < 4; ++ch) {
    if (ch < 3) {
      stageA(&Abuf[(ch + 1) & 1][0], hsK, rb, ch + 1, tid);
      stageB(&Bbuf[(ch + 1) & 1][0], hsK, cb, ch + 1, tid);
    }
    const ushort* At = &Abuf[ch & 1][0];
    const ushort* Bt = &Bbuf[ch & 1][0];
#pragma unroll
    for (int ks = 0; ks < 2; ++ks) {
      short8 bf[4];
#pragma unroll
      for (int cf = 0; cf < 4; ++cf)
        bf[cf] = *reinterpret_cast<const short8*>(
            Bt + ((ks * 4 + g) * 256 + wcol + cf * 16 + cl) * 8);
#pragma unroll
      for (int rf = 0; rf < 4; ++rf) {
        short8 a = *reinterpret_cast<const short8*>(
            At + ((ks * 4 + g) * 128 + wrow + rf * 16 + cl) * 8);
#pragma unroll
        for (int cf = 0; cf < 4; ++cf)
          acc[rf][cf] = __builtin_amdgcn_mfma_f32_16x16x32_bf16(
              a, bf[cf], acc[rf][cf], 0, 0, 0);
      }
    }
    __syncthreads();   // drains prefetch vmcnt + protects buffers
  }

  // epilogue: exp2 sums -> row partials (over cf,cl) / col partials (rf,q,g)
  float sr[16], cc[4];
#pragma unroll
  for (int i = 0; i < 16; ++i) sr[i] = 0.f;
#pragma unroll
  for (int i = 0; i < 4; ++i) cc[i] = 0.f;
#pragma unroll
  for (int rf = 0; rf < 4; ++rf)
#pragma unroll
    for (int cf = 0; cf < 4; ++cf)
#pragma unroll
      for (int q = 0; q < 4; ++q) {
        float e = __builtin_amdgcn_exp2f(acc[rf][cf][q]);
        sr[rf * 4 + q] += e;
        cc[cf] += e;
      }
#pragma unroll
  for (int i = 0; i < 16; ++i) {
#pragma unroll
    for (int d = 1; d <= 8; d <<= 1) sr[i] += __shfl_xor(sr[i], d);
  }
#pragma unroll
  for (int i = 0; i < 4; ++i) {
    cc[i] += __shfl_xor(cc[i], 16);
    cc[i] += __shfl_xor(cc[i], 32);
  }
  float* sred = reinterpret_cast<float*>(&Abuf[0][0]);  // [8 waves][64 rows]
  float* cred = sred + 512;                             // [8 waves][64 cols]
  if (cl == 0) {
#pragma unroll
    for (int rf = 0; rf < 4; ++rf)
#pragma unroll
      for (int q = 0; q < 4; ++q)
        sred[wave * 64 + rf * 16 + g * 4 + q] = sr[rf * 4 + q];
  }
  if (g == 0) {
#pragma unroll
    for (int cf = 0; cf < 4; ++cf) cred[wave * 64 + cf * 16 + cl] = cc[cf];
  }
  __syncthreads();
  if (tid < 128) {
    int r = tid, half = r >> 6, rl2 = r & 63;
    float rv = sred[(half * 4 + 0) * 64 + rl2] + sred[(half * 4 + 1) * 64 + rl2] +
               sred[(half * 4 + 2) * 64 + rl2] + sred[(half * 4 + 3) * 64 + rl2];
    rowpart[(size_t)cb * NB + rb * 128 + r] = rv;
  } else if (tid < 384 && !diagish) {
    int c2 = tid - 128;               // 0..255
    int cg2 = c2 >> 6, cl2 = c2 & 63;
    float cv = cred[cg2 * 64 + cl2] + cred[(cg2 + 4) * 64 + cl2];
    colpart[(size_t)rb * NB + cb * 256 + c2] = cv;
  }
}

// ---- per-row loss ----------------------------------------------------------
__global__ void rowloss_kernel(const ushort* __restrict__ hs,
                               const int* __restrict__ labels,
                               const float* __restrict__ Cs,
                               const float* __restrict__ cntf,
                               const float* __restrict__ rowpart,
                               const float* __restrict__ colpart,
                               const float* __restrict__ dbuf,
                               float2* __restrict__ rl) {
  int lane = threadIdx.x & 63, wave = threadIdx.x >> 6;
  int row = blockIdx.x * 4 + wave;
  int lbl = labels[row];
  ushort4 qb = reinterpret_cast<const ushort4*>(hs + (size_t)row * ND)[lane];
  float4 cv = reinterpret_cast<const float4*>(Cs + (size_t)lbl * ND)[lane];
  float dot = bf2f(qb.x) * cv.x + bf2f(qb.y) * cv.y +
              bf2f(qb.z) * cv.z + bf2f(qb.w) * cv.w;
#pragma unroll
  for (int d = 1; d <= 32; d <<= 1) dot += __shfl_xor(dot, d);

  int cr = row >> 8;                  // 256-col tile of this row
  float part = 0.f;
  if (lane < 32) {
    if (lane >= cr) part = rowpart[(size_t)lane * NB + row];
  } else {
    int k1 = (lane - 32) * 2;
    if (k1 < 2 * cr) part = colpart[(size_t)k1 * NB + row];
    if (k1 + 1 < 2 * cr) part += colpart[(size_t)(k1 + 1) * NB + row];
  }
#pragma unroll
  for (int d = 1; d <= 32; d <<= 1) part += __shfl_xor(part, d);

  if (lane == 0) {
    float dself = dbuf[row];
    float s = part - (1.0f - 1e-8f) * __builtin_amdgcn_exp2f(dself);
    float denom2 = log2f(s);
    float Sp2 = dot - dself;
    float n = cntf[lbl] - 1.0f;
    float li = 0.f, val = 0.f;
    if (n > 0.5f) { li = -LN2f * (Sp2 - n * denom2) / n; val = 1.f; }
    rl[row] = make_float2(li, val);
  }
}

__global__ __launch_bounds__(1024)
void reduce_kernel(const float2* __restrict__ rl, float* __restrict__ out) {
  int t = threadIdx.x;
  float L = 0.f, V = 0.f;
  for (int r = t; r < NB; r += 1024) { float2 p = rl[r]; L += p.x; V += p.y; }
#pragma unroll
  for (int d = 1; d <= 32; d <<= 1) { L += __shfl_xor(L, d); V += __shfl_xor(V, d); }
  __shared__ float sL[16], sV[16];
  if ((t & 63) == 0) { sL[t >> 6] = L; sV[t >> 6] = V; }
  __syncthreads();
  if (t == 0) {
    float Ls = 0.f, Vs = 0.f;
#pragma unroll
    for (int i = 0; i < 16; ++i) { Ls += sL[i]; Vs += sV[i]; }
    out[0] = Ls / fmaxf(Vs, 1.f);
  }
}

extern "C" void kernel_launch(void* const* d_in, const int* in_sizes, int n_in,
                              void* d_out, int out_size, void* d_ws, size_t ws_size,
                              hipStream_t stream) {
  const float* hidden = (const float*)d_in[0];
  const int* labels = (const int*)d_in[1];
  float* out = (float*)d_out;
  char* w = (char*)d_ws;
  ushort* hsK    = (ushort*)(w);                 // 4 MB
  ushort* hs     = (ushort*)(w + 4194304);       // 4 MB
  float* dbuf    = (float*)(w + 8388608);        // 32 KB
  float* Cs      = (float*)(w + 8421376);        // 100 KB
  float* cntf    = (float*)(w + 8523776);        // 512 B
  float* rowpart = (float*)(w + 8524288);        // 1 MB   (32 col-tiles x 8192)
  float* colpart = (float*)(w + 9572864);        // 2 MB   (64 row-tiles x 8192)
  float2* rl     = (float2*)(w + 11670016);      // 64 KB

  prep_kernel<<<NB / 4, 256, 0, stream>>>(hidden, hs, hsK, dbuf);
  main_kernel<<<NBT + 100, 512, 0, stream>>>(hsK, hs, labels, rowpart, colpart,
                                             Cs, cntf);
  rowloss_kernel<<<NB / 4, 256, 0, stream>>>(hs, labels, Cs, cntf, rowpart,
                                             colpart, dbuf, rl);
  reduce_kernel<<<1, 1024, 0, stream>>>(rl, out);
}